// Round 1
// baseline (383.347 us; speedup 1.0000x reference)
//
#include <hip/hip_runtime.h>
#include <hip/hip_bf16.h>
#include <cstdint>
#include <cstddef>

#define VOCAB 50000
#define DIM 128
#define BATCH 4096
#define CTX 10
#define NGROUPS 3125   // VOCAB/16
#define NCH 128        // N-chunk count (grid stride over N-groups)
#define MT 8           // M tiles of 512 rows (4 waves x 128 rows)

typedef short bf16x8 __attribute__((ext_vector_type(8)));
typedef float f32x4  __attribute__((ext_vector_type(4)));

// workspace layout (bytes)
#define WS_POOLED 0u                       // 4096*128*2      = 1,048,576
#define WS_WB     1048576u                 // 50000*128*2     = 12,800,000
#define WS_PART   13848576u                // NCH*BATCH*4     = 2,097,152
#define WS_LSE    15945728u                // BATCH*4         = 16,384
// total ~15.96 MB

// ---------------- pool: pooled[b][d] = mean_t emb[ctx[b][t]][d]  (bf16 out)
__global__ __launch_bounds__(256) void pool_kernel(
    const int* __restrict__ ctx, const float* __restrict__ emb,
    __hip_bfloat16* __restrict__ pooled) {
  int idx = blockIdx.x * 256 + threadIdx.x;      // 0 .. 4096*128-1
  int b = idx >> 7, d = idx & 127;
  const int* cb = ctx + b * CTX;
  float s = 0.f;
#pragma unroll
  for (int t = 0; t < CTX; ++t) s += emb[(size_t)cb[t] * DIM + d];
  pooled[idx] = __float2bfloat16(s * 0.1f);
}

// ---------------- convert W fp32 -> bf16
__global__ __launch_bounds__(256) void convw_kernel(
    const float* __restrict__ W, __hip_bfloat16* __restrict__ Wb) {
  int idx = blockIdx.x * 256 + threadIdx.x;      // one float4 per thread
  float4 v = reinterpret_cast<const float4*>(W)[idx];
  __hip_bfloat16 o[4];
  o[0] = __float2bfloat16(v.x); o[1] = __float2bfloat16(v.y);
  o[2] = __float2bfloat16(v.z); o[3] = __float2bfloat16(v.w);
  reinterpret_cast<ushort4*>(Wb)[idx] = *reinterpret_cast<ushort4*>(o);
}

// ---------------- pass1: per-row sum(exp(logit)) partials
__global__ __launch_bounds__(256) void pass1_kernel(
    const __hip_bfloat16* __restrict__ pooled,
    const __hip_bfloat16* __restrict__ Wb,
    float* __restrict__ part) {
  int blk = blockIdx.x;          // nc*8 + mt, consecutive blocks share nc
  int mt = blk & 7;
  int nc = blk >> 3;             // 0..127
  int wave = threadIdx.x >> 6, lane = threadIdx.x & 63;
  int rowbase = mt * 512 + wave * 128;
  int lr = lane & 15, lk = lane >> 4;

  bf16x8 Afr[8][4];
#pragma unroll
  for (int mg = 0; mg < 8; ++mg)
#pragma unroll
    for (int ks = 0; ks < 4; ++ks)
      Afr[mg][ks] = *reinterpret_cast<const bf16x8*>(
          pooled + (size_t)(rowbase + mg * 16 + lr) * DIM + lk * 8 + ks * 32);

  float s[8][4];
#pragma unroll
  for (int mg = 0; mg < 8; ++mg)
#pragma unroll
    for (int i = 0; i < 4; ++i) s[mg][i] = 0.f;

  for (int g = nc; g < NGROUPS; g += NCH) {
    const __hip_bfloat16* Bp = Wb + (size_t)(g * 16 + lr) * DIM + lk * 8;
    bf16x8 Bfr[4];
#pragma unroll
    for (int ks = 0; ks < 4; ++ks)
      Bfr[ks] = *reinterpret_cast<const bf16x8*>(Bp + ks * 32);
#pragma unroll
    for (int mg = 0; mg < 8; ++mg) {
      f32x4 acc = {0.f, 0.f, 0.f, 0.f};
#pragma unroll
      for (int ks = 0; ks < 4; ++ks)
        acc = __builtin_amdgcn_mfma_f32_16x16x32_bf16(Afr[mg][ks], Bfr[ks], acc, 0, 0, 0);
#pragma unroll
      for (int i = 0; i < 4; ++i) s[mg][i] += __expf(acc[i]);
    }
  }

  // reduce across the 16 column-lanes (xor masks 1,2,4,8 stay within group)
#pragma unroll
  for (int mg = 0; mg < 8; ++mg)
#pragma unroll
    for (int i = 0; i < 4; ++i) {
      float v = s[mg][i];
      v += __shfl_xor(v, 1, 64);
      v += __shfl_xor(v, 2, 64);
      v += __shfl_xor(v, 4, 64);
      v += __shfl_xor(v, 8, 64);
      s[mg][i] = v;
    }
  if (lr == 0) {
#pragma unroll
    for (int mg = 0; mg < 8; ++mg)
#pragma unroll
      for (int i = 0; i < 4; ++i)
        part[nc * BATCH + rowbase + mg * 16 + lk * 4 + i] = s[mg][i];
  }
}

// ---------------- reduce: lse[b] = log(sum_nc part[nc][b])
__global__ __launch_bounds__(256) void reduce_kernel(
    const float* __restrict__ part, float* __restrict__ lse) {
  int b = blockIdx.x * 256 + threadIdx.x;
  float s = 0.f;
  for (int nc = 0; nc < NCH; ++nc) s += part[nc * BATCH + b];
  lse[b] = __logf(s);
}

// ---------------- pass2: out[b][v] = logit - lse[b]
__global__ __launch_bounds__(256) void pass2_kernel(
    const __hip_bfloat16* __restrict__ pooled,
    const __hip_bfloat16* __restrict__ Wb,
    const float* __restrict__ lse, float* __restrict__ out) {
  int blk = blockIdx.x;
  int mt = blk & 7;
  int nc = blk >> 3;
  int wave = threadIdx.x >> 6, lane = threadIdx.x & 63;
  int rowbase = mt * 512 + wave * 128;
  int lr = lane & 15, lk = lane >> 4;

  bf16x8 Afr[8][4];
#pragma unroll
  for (int mg = 0; mg < 8; ++mg)
#pragma unroll
    for (int ks = 0; ks < 4; ++ks)
      Afr[mg][ks] = *reinterpret_cast<const bf16x8*>(
          pooled + (size_t)(rowbase + mg * 16 + lr) * DIM + lk * 8 + ks * 32);

  float lse_r[8][4];
#pragma unroll
  for (int mg = 0; mg < 8; ++mg)
#pragma unroll
    for (int i = 0; i < 4; ++i)
      lse_r[mg][i] = lse[rowbase + mg * 16 + lk * 4 + i];

  size_t obase = (size_t)(rowbase + lk * 4) * VOCAB + lr;

  for (int g = nc; g < NGROUPS; g += NCH) {
    const __hip_bfloat16* Bp = Wb + (size_t)(g * 16 + lr) * DIM + lk * 8;
    bf16x8 Bfr[4];
#pragma unroll
    for (int ks = 0; ks < 4; ++ks)
      Bfr[ks] = *reinterpret_cast<const bf16x8*>(Bp + ks * 32);
#pragma unroll
    for (int mg = 0; mg < 8; ++mg) {
      f32x4 acc = {0.f, 0.f, 0.f, 0.f};
#pragma unroll
      for (int ks = 0; ks < 4; ++ks)
        acc = __builtin_amdgcn_mfma_f32_16x16x32_bf16(Afr[mg][ks], Bfr[ks], acc, 0, 0, 0);
#pragma unroll
      for (int i = 0; i < 4; ++i)
        out[obase + (size_t)(mg * 16 + i) * VOCAB + g * 16] = acc[i] - lse_r[mg][i];
    }
  }
}

extern "C" void kernel_launch(void* const* d_in, const int* in_sizes, int n_in,
                              void* d_out, int out_size, void* d_ws, size_t ws_size,
                              hipStream_t stream) {
  const int* ctx = (const int*)d_in[0];
  const float* emb = (const float*)d_in[1];
  const float* W = (const float*)d_in[2];
  float* out = (float*)d_out;

  char* ws = (char*)d_ws;
  __hip_bfloat16* pooled = (__hip_bfloat16*)(ws + WS_POOLED);
  __hip_bfloat16* Wb = (__hip_bfloat16*)(ws + WS_WB);
  float* part = (float*)(ws + WS_PART);
  float* lse = (float*)(ws + WS_LSE);

  pool_kernel<<<(BATCH * DIM) / 256, 256, 0, stream>>>(ctx, emb, pooled);
  convw_kernel<<<(VOCAB * DIM) / (256 * 4), 256, 0, stream>>>(W, Wb);
  pass1_kernel<<<NCH * MT, 256, 0, stream>>>(pooled, Wb, part);
  reduce_kernel<<<BATCH / 256, 256, 0, stream>>>(part, lse);
  pass2_kernel<<<NCH * MT, 256, 0, stream>>>(pooled, Wb, lse, out);
}